// Round 1
// baseline (1425.149 us; speedup 1.0000x reference)
//
#include <hip/hip_runtime.h>

#define HW    96
#define NPIX  9216        // 96*96
#define NCH   64          // C
#define INNER 3
#define NDIL  3
#define BB    2           // batch

// ---------------------------------------------------------------------------
// Kernel 1: x_red = 1x1 conv (64 -> 3 channels)
// ---------------------------------------------------------------------------
__global__ void k_reduce(const float* __restrict__ x, const float* __restrict__ w_red,
                         const float* __restrict__ b_red, float* __restrict__ xred) {
    int pix = blockIdx.x * blockDim.x + threadIdx.x;
    if (pix >= BB * NPIX) return;
    int b = pix / NPIX, n = pix % NPIX;
    float a0 = b_red[0], a1 = b_red[1], a2 = b_red[2];
    const float* xb = x + (size_t)b * NCH * NPIX + n;
    #pragma unroll
    for (int c = 0; c < NCH; ++c) {
        float xv = xb[(size_t)c * NPIX];          // coalesced across threads
        a0 = fmaf(w_red[0 * NCH + c], xv, a0);    // uniform idx -> scalar loads
        a1 = fmaf(w_red[1 * NCH + c], xv, a1);
        a2 = fmaf(w_red[2 * NCH + c], xv, a2);
    }
    float* xr = xred + (size_t)b * INNER * NPIX + n;
    xr[0 * NPIX] = a0; xr[1 * NPIX] = a1; xr[2 * NPIX] = a2;
}

// ---------------------------------------------------------------------------
// Kernel 2: dilated convs + C4 transforms + 54 products + 1x1 fuse conv,
// all per-pixel; writes tokens row-major [B][N][C] (attention layout).
// ---------------------------------------------------------------------------
__global__ void k_tokens(const float* __restrict__ xred,
                         const float* __restrict__ w_dil, const float* __restrict__ b_dil,
                         const float* __restrict__ w_fuse, const float* __restrict__ b_fuse,
                         float* __restrict__ tokens) {
    __shared__ float wf[54 * NCH];   // 13.8 KB, read as wave-uniform broadcast
    __shared__ float bf[NCH];
    for (int i = threadIdx.x; i < 54 * NCH; i += blockDim.x) wf[i] = w_fuse[i];
    for (int i = threadIdx.x; i < NCH; i += blockDim.x)      bf[i] = b_fuse[i];
    __syncthreads();

    int pix = blockIdx.x * blockDim.x + threadIdx.x;
    if (pix >= BB * NPIX) return;
    int b = pix / NPIX, n = pix % NPIX;
    int h = n / HW, w = n % HW;
    const float* xr = xred + (size_t)b * INNER * NPIX;

    // C4 transforms of x_red at this pixel (identity, flipW, flipH, rot90 k=1,2,3)
    float tf[6][INNER];
    #pragma unroll
    for (int o = 0; o < INNER; ++o) {
        const float* xo = xr + o * NPIX;
        tf[0][o] = xo[h * HW + w];
        tf[1][o] = xo[h * HW + (HW - 1 - w)];
        tf[2][o] = xo[(HW - 1 - h) * HW + w];
        tf[3][o] = xo[w * HW + (HW - 1 - h)];            // rot90 k=1: out[h,w]=in[w, W-1-h]
        tf[4][o] = xo[(HW - 1 - h) * HW + (HW - 1 - w)]; // rot90 k=2
        tf[5][o] = xo[(HW - 1 - w) * HW + h];            // rot90 k=3: out[h,w]=in[H-1-w, h]
    }

    // dilated 3x3 convs (d = 1,2,3), zero padding
    float co[NDIL][INNER];
    #pragma unroll
    for (int i = 0; i < NDIL; ++i) {
        int d = i + 1;
        #pragma unroll
        for (int o = 0; o < INNER; ++o) co[i][o] = b_dil[i * INNER + o];
        #pragma unroll
        for (int ci = 0; ci < INNER; ++ci) {
            const float* xo = xr + ci * NPIX;
            #pragma unroll
            for (int kh = 0; kh < 3; ++kh) {
                int hh = h + (kh - 1) * d;
                #pragma unroll
                for (int kw = 0; kw < 3; ++kw) {
                    int ww = w + (kw - 1) * d;
                    float v = ((unsigned)hh < HW && (unsigned)ww < HW) ? xo[hh * HW + ww] : 0.f;
                    #pragma unroll
                    for (int o = 0; o < INNER; ++o)
                        co[i][o] = fmaf(w_dil[((i * INNER + o) * INNER + ci) * 9 + kh * 3 + kw],
                                        v, co[i][o]);
                }
            }
        }
    }

    // 54 feature products, channel order (i*6 + t)*3 + o  (matches concat order)
    float f[54];
    #pragma unroll
    for (int i = 0; i < NDIL; ++i)
        #pragma unroll
        for (int t = 0; t < 6; ++t)
            #pragma unroll
            for (int o = 0; o < INNER; ++o)
                f[(i * 6 + t) * INNER + o] = co[i][o] * tf[t][o];

    // 1x1 fuse conv -> tokens[b][n][c]
    float* tok = tokens + ((size_t)b * NPIX + n) * NCH;
    #pragma unroll 4
    for (int c = 0; c < NCH; ++c) {
        float acc = bf[c];
        #pragma unroll
        for (int j = 0; j < 54; ++j) acc = fmaf(wf[c * 54 + j], f[j], acc);
        tok[c] = acc;
    }
}

// ---------------------------------------------------------------------------
// Kernel 3: flash attention partials. Q=K=V=tokens. Thread-per-query,
// 64-query blocks, 64-key LDS tiles, keys split into P partitions.
// Partials: pm/pl [B][P][N], pacc [B][P][N][C].
// ---------------------------------------------------------------------------
__global__ __launch_bounds__(64) void
k_attn(const float* __restrict__ tokens, float* __restrict__ pm, float* __restrict__ pl,
       float* __restrict__ pacc, int P, int KP) {
    const int QB = NPIX / 64;                 // 144 query chunks
    int bid = blockIdx.x;
    int qc = bid % QB; int rest = bid / QB;
    int p = rest % P;  int b = rest / P;
    int row = qc * 64 + threadIdx.x;

    const float* tb = tokens + (size_t)b * NPIX * NCH;
    float q[NCH];
    {
        const float4* qr = (const float4*)(tb + (size_t)row * NCH);
        #pragma unroll
        for (int v = 0; v < 16; ++v) {
            float4 t = qr[v];
            q[4*v+0] = t.x * 0.125f;  // fold 1/sqrt(64) into q
            q[4*v+1] = t.y * 0.125f;
            q[4*v+2] = t.z * 0.125f;
            q[4*v+3] = t.w * 0.125f;
        }
    }
    float m = -1e30f, l = 0.f;
    float acc[NCH];
    #pragma unroll
    for (int c = 0; c < NCH; ++c) acc[c] = 0.f;

    __shared__ float kl[64 * NCH];            // 16 KB key/value tile
    int k0 = p * KP;
    for (int kt = 0; kt < KP; kt += 64) {
        __syncthreads();
        {   // thread t stages key row k0+kt+t (256 B contiguous)
            const float4* src = (const float4*)(tb + (size_t)(k0 + kt + threadIdx.x) * NCH);
            float4* dst = (float4*)(kl + threadIdx.x * NCH);
            #pragma unroll
            for (int v = 0; v < 16; ++v) dst[v] = src[v];
        }
        __syncthreads();
        for (int j = 0; j < 64; ++j) {
            const float4* kr = (const float4*)(kl + j * NCH);  // broadcast reads
            float d0 = 0.f, d1 = 0.f, d2 = 0.f, d3 = 0.f;
            #pragma unroll
            for (int v = 0; v < 16; ++v) {
                float4 kv = kr[v];
                d0 = fmaf(q[4*v+0], kv.x, d0);
                d1 = fmaf(q[4*v+1], kv.y, d1);
                d2 = fmaf(q[4*v+2], kv.z, d2);
                d3 = fmaf(q[4*v+3], kv.w, d3);
            }
            float s = (d0 + d1) + (d2 + d3);
            if (s > m) {                       // rare after warmup
                float sc = __expf(m - s);      // first iter: exp(-huge)=0 zeroes init
                l *= sc;
                #pragma unroll
                for (int c = 0; c < NCH; ++c) acc[c] *= sc;
                m = s;
            }
            float pr = __expf(s - m);
            l += pr;
            #pragma unroll
            for (int v = 0; v < 16; ++v) {     // V == K tile
                float4 kv = kr[v];
                acc[4*v+0] = fmaf(pr, kv.x, acc[4*v+0]);
                acc[4*v+1] = fmaf(pr, kv.y, acc[4*v+1]);
                acc[4*v+2] = fmaf(pr, kv.z, acc[4*v+2]);
                acc[4*v+3] = fmaf(pr, kv.w, acc[4*v+3]);
            }
        }
    }
    size_t base = ((size_t)b * P + p) * NPIX + row;
    pm[base] = m; pl[base] = l;
    float4* pa = (float4*)(pacc + base * NCH);
    #pragma unroll
    for (int v = 0; v < 16; ++v)
        pa[v] = make_float4(acc[4*v+0], acc[4*v+1], acc[4*v+2], acc[4*v+3]);
}

// ---------------------------------------------------------------------------
// Kernel 4: merge P partials, apply residual: out = x + 0.2 * attn_out (NCHW)
// ---------------------------------------------------------------------------
__global__ void k_combine(const float* __restrict__ x, const float* __restrict__ pm,
                          const float* __restrict__ pl, const float* __restrict__ pacc,
                          float* __restrict__ out, int P) {
    int idx = blockIdx.x * blockDim.x + threadIdx.x;
    if (idx >= BB * NPIX) return;
    int b = idx / NPIX, n = idx % NPIX;
    float M = -1e30f;
    for (int p = 0; p < P; ++p) M = fmaxf(M, pm[((size_t)b * P + p) * NPIX + n]);
    float L = 0.f;
    float o[NCH];
    #pragma unroll
    for (int c = 0; c < NCH; ++c) o[c] = 0.f;
    for (int p = 0; p < P; ++p) {
        size_t base = ((size_t)b * P + p) * NPIX + n;
        float fct = __expf(pm[base] - M);
        L += pl[base] * fct;
        const float4* pa = (const float4*)(pacc + base * NCH);
        #pragma unroll
        for (int v = 0; v < 16; ++v) {
            float4 t = pa[v];
            o[4*v+0] = fmaf(fct, t.x, o[4*v+0]);
            o[4*v+1] = fmaf(fct, t.y, o[4*v+1]);
            o[4*v+2] = fmaf(fct, t.z, o[4*v+2]);
            o[4*v+3] = fmaf(fct, t.w, o[4*v+3]);
        }
    }
    float inv = 0.2f / L;
    const float* xb = x + (size_t)b * NCH * NPIX + n;
    float* ob = out + (size_t)b * NCH * NPIX + n;
    #pragma unroll
    for (int c = 0; c < NCH; ++c)
        ob[(size_t)c * NPIX] = fmaf(inv, o[c], xb[(size_t)c * NPIX]);  // coalesced per c
}

// ---------------------------------------------------------------------------
extern "C" void kernel_launch(void* const* d_in, const int* in_sizes, int n_in,
                              void* d_out, int out_size, void* d_ws, size_t ws_size,
                              hipStream_t stream) {
    const float* x      = (const float*)d_in[0];
    const float* w_red  = (const float*)d_in[1];
    const float* b_red  = (const float*)d_in[2];
    const float* w_dil  = (const float*)d_in[3];
    const float* b_dil  = (const float*)d_in[4];
    const float* w_fuse = (const float*)d_in[5];
    const float* b_fuse = (const float*)d_in[6];
    float* out = (float*)d_out;
    float* ws  = (float*)d_ws;

    // Workspace layout (floats): xred | tokens | pm | pl | pacc
    const size_t XRED_N = (size_t)BB * INNER * NPIX;   //   55,296
    const size_t TOK_N  = (size_t)BB * NPIX * NCH;     // 1,179,648
    // pick largest key-partition count P that fits ws (deterministic per call)
    int P = 0;
    const int cands[4] = {8, 4, 2, 1};
    for (int ci = 0; ci < 4; ++ci) {
        int cp = cands[ci];
        size_t need = (XRED_N + TOK_N + (size_t)BB * cp * NPIX * (2 + NCH)) * sizeof(float);
        if (ws_size >= need) { P = cp; break; }
    }
    if (P == 0) return;  // ws too small even for P=1 (9.9 MB) -> fail loudly

    float* xred   = ws;
    float* tokens = xred + XRED_N;
    float* pm     = tokens + TOK_N;
    float* pl     = pm + (size_t)BB * P * NPIX;
    float* pacc   = pl + (size_t)BB * P * NPIX;

    k_reduce <<<(BB * NPIX + 255) / 256, 256, 0, stream>>>(x, w_red, b_red, xred);
    k_tokens <<<(BB * NPIX + 255) / 256, 256, 0, stream>>>(xred, w_dil, b_dil,
                                                           w_fuse, b_fuse, tokens);
    k_attn   <<<BB * P * (NPIX / 64), 64, 0, stream>>>(tokens, pm, pl, pacc, P, NPIX / P);
    k_combine<<<(BB * NPIX + 255) / 256, 256, 0, stream>>>(x, pm, pl, pacc, out, P);
}

// Round 2
// 315.112 us; speedup vs baseline: 4.5227x; 4.5227x over previous
//
#include <hip/hip_runtime.h>

#define HW    96
#define NPIX  9216        // 96*96
#define NCH   64          // C
#define INNER 3
#define NDIL  3
#define BB    2           // batch

typedef __attribute__((ext_vector_type(8))) short short8;  // 8 bf16 (4 VGPRs)
typedef __attribute__((ext_vector_type(4))) float f32x4;   // 4 fp32 acc

__device__ __forceinline__ ushort f2bf_rne(float f) {
    unsigned u = __float_as_uint(f);
    u += 0x7fffu + ((u >> 16) & 1u);
    return (ushort)(u >> 16);
}
__device__ __forceinline__ ushort f2bf_trunc(float f) {   // P in [0,1]; bias cancels in ratio
    return (ushort)(__float_as_uint(f) >> 16);
}

// ---------------------------------------------------------------------------
// Kernel 1: x_red = 1x1 conv (64 -> 3 channels)
// ---------------------------------------------------------------------------
__global__ void k_reduce(const float* __restrict__ x, const float* __restrict__ w_red,
                         const float* __restrict__ b_red, float* __restrict__ xred) {
    int pix = blockIdx.x * blockDim.x + threadIdx.x;
    if (pix >= BB * NPIX) return;
    int b = pix / NPIX, n = pix % NPIX;
    float a0 = b_red[0], a1 = b_red[1], a2 = b_red[2];
    const float* xb = x + (size_t)b * NCH * NPIX + n;
    #pragma unroll
    for (int c = 0; c < NCH; ++c) {
        float xv = xb[(size_t)c * NPIX];
        a0 = fmaf(w_red[0 * NCH + c], xv, a0);
        a1 = fmaf(w_red[1 * NCH + c], xv, a1);
        a2 = fmaf(w_red[2 * NCH + c], xv, a2);
    }
    float* xr = xred + (size_t)b * INNER * NPIX + n;
    xr[0 * NPIX] = a0; xr[1 * NPIX] = a1; xr[2 * NPIX] = a2;
}

// ---------------------------------------------------------------------------
// Kernel 2: dilated convs + C4 transforms + 54 products + 1x1 fuse conv.
// Writes tokens row-major [B][N][C].
// ---------------------------------------------------------------------------
__global__ void k_tokens(const float* __restrict__ xred,
                         const float* __restrict__ w_dil, const float* __restrict__ b_dil,
                         const float* __restrict__ w_fuse, const float* __restrict__ b_fuse,
                         float* __restrict__ tokens) {
    __shared__ float wf[54 * NCH];
    __shared__ float bf[NCH];
    for (int i = threadIdx.x; i < 54 * NCH; i += blockDim.x) wf[i] = w_fuse[i];
    for (int i = threadIdx.x; i < NCH; i += blockDim.x)      bf[i] = b_fuse[i];
    __syncthreads();

    int pix = blockIdx.x * blockDim.x + threadIdx.x;
    if (pix >= BB * NPIX) return;
    int b = pix / NPIX, n = pix % NPIX;
    int h = n / HW, w = n % HW;
    const float* xr = xred + (size_t)b * INNER * NPIX;

    float tf[6][INNER];
    #pragma unroll
    for (int o = 0; o < INNER; ++o) {
        const float* xo = xr + o * NPIX;
        tf[0][o] = xo[h * HW + w];
        tf[1][o] = xo[h * HW + (HW - 1 - w)];
        tf[2][o] = xo[(HW - 1 - h) * HW + w];
        tf[3][o] = xo[w * HW + (HW - 1 - h)];
        tf[4][o] = xo[(HW - 1 - h) * HW + (HW - 1 - w)];
        tf[5][o] = xo[(HW - 1 - w) * HW + h];
    }

    float co[NDIL][INNER];
    #pragma unroll
    for (int i = 0; i < NDIL; ++i) {
        int d = i + 1;
        #pragma unroll
        for (int o = 0; o < INNER; ++o) co[i][o] = b_dil[i * INNER + o];
        #pragma unroll
        for (int ci = 0; ci < INNER; ++ci) {
            const float* xo = xr + ci * NPIX;
            #pragma unroll
            for (int kh = 0; kh < 3; ++kh) {
                int hh = h + (kh - 1) * d;
                #pragma unroll
                for (int kw = 0; kw < 3; ++kw) {
                    int ww = w + (kw - 1) * d;
                    float v = ((unsigned)hh < HW && (unsigned)ww < HW) ? xo[hh * HW + ww] : 0.f;
                    #pragma unroll
                    for (int o = 0; o < INNER; ++o)
                        co[i][o] = fmaf(w_dil[((i * INNER + o) * INNER + ci) * 9 + kh * 3 + kw],
                                        v, co[i][o]);
                }
            }
        }
    }

    float f[54];
    #pragma unroll
    for (int i = 0; i < NDIL; ++i)
        #pragma unroll
        for (int t = 0; t < 6; ++t)
            #pragma unroll
            for (int o = 0; o < INNER; ++o)
                f[(i * 6 + t) * INNER + o] = co[i][o] * tf[t][o];

    float* tok = tokens + ((size_t)b * NPIX + n) * NCH;
    #pragma unroll 4
    for (int c = 0; c < NCH; ++c) {
        float acc = bf[c];
        #pragma unroll
        for (int j = 0; j < 54; ++j) acc = fmaf(wf[c * 54 + j], f[j], acc);
        tok[c] = acc;
    }
}

// ---------------------------------------------------------------------------
// Kernel 3: MFMA flash attention partials (bf16 16x16x32).
// Transposed formulation: S^T = K·Q^T  (softmax per col q=lane&15, per-lane scalar),
// then O^T = V^T·P^T. 4 waves/wg x 64 queries/wave; 64-key tiles; key split P ways.
// LDS tiles chunk-XOR-swizzled (chunk' = chunk ^ (row&7)) against bank conflicts.
// exp2 domain: 0.125*log2(e) folded into Q.
// Partials: pm/pl [B][P][N] (base-2 m), pacc [B][P][N][C].
// ---------------------------------------------------------------------------
__global__ __launch_bounds__(256, 2) void
k_attn(const float* __restrict__ tokens, float* __restrict__ pm, float* __restrict__ pl,
       float* __restrict__ pacc, int P, int KP) {
    __shared__ ushort kt[64 * 64];      // [key][ch]  bf16, 8 KB
    __shared__ ushort vt[64 * 64];      // [ch][key]  bf16, 8 KB
    __shared__ ushort pt[4][64 * 64];   // per-wave P [q][key], 32 KB

    const int QW = NPIX / 256;          // 36 query chunks per batch
    int bid = blockIdx.x;
    int qc = bid % QW; int rest = bid / QW;
    int p = rest % P;  int b = rest / P;
    int tid = threadIdx.x;
    int wv = tid >> 6, lane = tid & 63;
    int quad = lane >> 4, l15 = lane & 15;

    const float* tb = tokens + (size_t)b * NPIX * NCH;
    int qwave = qc * 256 + wv * 64;

    // Persistent Q fragments: B operand of S^T (B[k=ch][n=q]: lane n=l15, k=quad*8+j+32kc)
    short8 qf[4][2];
    const float scale = 0.125f * 1.44269504088896340736f;  // 1/sqrt(C) * log2(e)
    #pragma unroll
    for (int n = 0; n < 4; ++n) {
        const float* qr = tb + (size_t)(qwave + 16 * n + l15) * NCH + quad * 8;
        #pragma unroll
        for (int kc = 0; kc < 2; ++kc) {
            float4 a = *(const float4*)(qr + 32 * kc);
            float4 c = *(const float4*)(qr + 32 * kc + 4);
            short8 f;
            f[0] = f2bf_rne(a.x * scale); f[1] = f2bf_rne(a.y * scale);
            f[2] = f2bf_rne(a.z * scale); f[3] = f2bf_rne(a.w * scale);
            f[4] = f2bf_rne(c.x * scale); f[5] = f2bf_rne(c.y * scale);
            f[6] = f2bf_rne(c.z * scale); f[7] = f2bf_rne(c.w * scale);
            qf[n][kc] = f;
        }
    }

    f32x4 O[4][4];                      // O^T acc: D[c=16m+quad*4+reg][q=16n+l15]
    #pragma unroll
    for (int m = 0; m < 4; ++m)
        #pragma unroll
        for (int n = 0; n < 4; ++n) O[m][n] = (f32x4){0.f, 0.f, 0.f, 0.f};
    float mrun[4], lrun[4];
    #pragma unroll
    for (int n = 0; n < 4; ++n) { mrun[n] = -1e30f; lrun[n] = 0.f; }

    int r4 = (tid >> 4) * 4;            // staging: key group
    int c4 = (tid & 15) * 4;            // staging: channel group

    int k0 = p * KP;
    for (int kt0 = 0; kt0 < KP; kt0 += 64) {
        __syncthreads();                // all waves done reading previous kt/vt
        {   // stage 64 keys x 64 ch: fp32 -> bf16, write kt [key][ch] and vt [ch][key]
            float4 rowv[4];
            const float* src = tb + (size_t)(k0 + kt0 + r4) * NCH + c4;
            #pragma unroll
            for (int i = 0; i < 4; ++i) rowv[i] = *(const float4*)(src + (size_t)i * NCH);
            #pragma unroll
            for (int i = 0; i < 4; ++i) {
                int row = r4 + i;
                int cs = (c4 >> 3) ^ (row & 7);
                ushort4 w;
                w.x = f2bf_rne(rowv[i].x); w.y = f2bf_rne(rowv[i].y);
                w.z = f2bf_rne(rowv[i].z); w.w = f2bf_rne(rowv[i].w);
                *(ushort4*)&kt[row * 64 + cs * 8 + ((c4 >> 2) & 1) * 4] = w;
            }
            #pragma unroll
            for (int j = 0; j < 4; ++j) {
                int ch = c4 + j;
                int cs = (r4 >> 3) ^ (ch & 7);
                ushort4 w;
                w.x = f2bf_rne((&rowv[0].x)[j]); w.y = f2bf_rne((&rowv[1].x)[j]);
                w.z = f2bf_rne((&rowv[2].x)[j]); w.w = f2bf_rne((&rowv[3].x)[j]);
                *(ushort4*)&vt[ch * 64 + cs * 8 + ((r4 >> 2) & 1) * 4] = w;
            }
        }
        __syncthreads();

        // S^T = K·Q^T : D[key][q]; A from kt (lane m=key=16m+l15, k=ch)
        f32x4 S[4][4];
        #pragma unroll
        for (int m = 0; m < 4; ++m)
            #pragma unroll
            for (int n = 0; n < 4; ++n) S[m][n] = (f32x4){0.f, 0.f, 0.f, 0.f};
        #pragma unroll
        for (int kc = 0; kc < 2; ++kc) {
            short8 kf[4];
            #pragma unroll
            for (int m = 0; m < 4; ++m) {
                int row = 16 * m + l15;
                int cs = (quad + 4 * kc) ^ (row & 7);
                kf[m] = *(const short8*)&kt[row * 64 + cs * 8];
            }
            #pragma unroll
            for (int n = 0; n < 4; ++n)
                #pragma unroll
                for (int m = 0; m < 4; ++m)
                    S[m][n] = __builtin_amdgcn_mfma_f32_16x16x32_bf16(kf[m], qf[n][kc],
                                                                      S[m][n], 0, 0, 0);
        }

        // online softmax, per query col (per-lane scalar); keys live in (m, quad, reg)
        #pragma unroll
        for (int n = 0; n < 4; ++n) {
            float tmax = S[0][n][0];
            #pragma unroll
            for (int m = 0; m < 4; ++m)
                #pragma unroll
                for (int r = 0; r < 4; ++r) tmax = fmaxf(tmax, S[m][n][r]);
            tmax = fmaxf(tmax, __shfl_xor(tmax, 16, 64));   // quad butterfly
            tmax = fmaxf(tmax, __shfl_xor(tmax, 32, 64));
            float mn = fmaxf(mrun[n], tmax);
            float alpha = exp2f(mrun[n] - mn);
            mrun[n] = mn;
            lrun[n] *= alpha;
            #pragma unroll
            for (int m = 0; m < 4; ++m) {
                O[m][n][0] *= alpha; O[m][n][1] *= alpha;
                O[m][n][2] *= alpha; O[m][n][3] *= alpha;
            }
            int q = 16 * n + l15;
            #pragma unroll
            for (int m = 0; m < 4; ++m) {
                float p0 = exp2f(S[m][n][0] - mn), p1 = exp2f(S[m][n][1] - mn);
                float p2 = exp2f(S[m][n][2] - mn), p3 = exp2f(S[m][n][3] - mn);
                lrun[n] += (p0 + p1) + (p2 + p3);
                ushort4 w;
                w.x = f2bf_trunc(p0); w.y = f2bf_trunc(p1);
                w.z = f2bf_trunc(p2); w.w = f2bf_trunc(p3);
                int chunk = 2 * m + (quad >> 1);            // keys 16m+quad*4..+3
                int cs = chunk ^ (q & 7);
                *(ushort4*)&pt[wv][q * 64 + cs * 8 + (quad & 1) * 4] = w;
            }
        }

        // O^T += V^T·P^T : D[c][q]; A from vt (m=ch), B from pt (n=q, k=key)
        #pragma unroll
        for (int kc = 0; kc < 2; ++kc) {
            short8 af[4];
            #pragma unroll
            for (int m = 0; m < 4; ++m) {
                int ch = 16 * m + l15;
                int cs = (quad + 4 * kc) ^ (ch & 7);
                af[m] = *(const short8*)&vt[ch * 64 + cs * 8];
            }
            #pragma unroll
            for (int n = 0; n < 4; ++n) {
                int q = 16 * n + l15;
                int cs = (quad + 4 * kc) ^ (q & 7);
                short8 bfr = *(const short8*)&pt[wv][q * 64 + cs * 8];
                #pragma unroll
                for (int m = 0; m < 4; ++m)
                    O[m][n] = __builtin_amdgcn_mfma_f32_16x16x32_bf16(af[m], bfr,
                                                                      O[m][n], 0, 0, 0);
            }
        }
    }

    // l: disjoint key subsets per quad -> butterfly sum
    #pragma unroll
    for (int n = 0; n < 4; ++n) {
        lrun[n] += __shfl_xor(lrun[n], 16, 64);
        lrun[n] += __shfl_xor(lrun[n], 32, 64);
    }
    size_t bpb = ((size_t)b * P + p) * NPIX;
    if (quad == 0) {
        #pragma unroll
        for (int n = 0; n < 4; ++n) {
            int qg = qwave + 16 * n + l15;
            pm[bpb + qg] = mrun[n];
            pl[bpb + qg] = lrun[n];
        }
    }
    #pragma unroll
    for (int n = 0; n < 4; ++n) {
        int qg = qwave + 16 * n + l15;
        float* dst = pacc + (bpb + qg) * NCH;
        #pragma unroll
        for (int m = 0; m < 4; ++m)
            *(float4*)(dst + 16 * m + quad * 4) =
                make_float4(O[m][n][0], O[m][n][1], O[m][n][2], O[m][n][3]);
    }
}

// ---------------------------------------------------------------------------
// Kernel 4: merge P partials (exp2 domain), residual: out = x + 0.2*attn (NCHW)
// ---------------------------------------------------------------------------
__global__ void k_combine(const float* __restrict__ x, const float* __restrict__ pm,
                          const float* __restrict__ pl, const float* __restrict__ pacc,
                          float* __restrict__ out, int P) {
    int idx = blockIdx.x * blockDim.x + threadIdx.x;
    if (idx >= BB * NPIX) return;
    int b = idx / NPIX, n = idx % NPIX;
    float M = -1e30f;
    for (int p = 0; p < P; ++p) M = fmaxf(M, pm[((size_t)b * P + p) * NPIX + n]);
    float L = 0.f;
    float o[NCH];
    #pragma unroll
    for (int c = 0; c < NCH; ++c) o[c] = 0.f;
    for (int p = 0; p < P; ++p) {
        size_t base = ((size_t)b * P + p) * NPIX + n;
        float fct = exp2f(pm[base] - M);
        L += pl[base] * fct;
        const float4* pa = (const float4*)(pacc + base * NCH);
        #pragma unroll
        for (int v = 0; v < 16; ++v) {
            float4 t = pa[v];
            o[4*v+0] = fmaf(fct, t.x, o[4*v+0]);
            o[4*v+1] = fmaf(fct, t.y, o[4*v+1]);
            o[4*v+2] = fmaf(fct, t.z, o[4*v+2]);
            o[4*v+3] = fmaf(fct, t.w, o[4*v+3]);
        }
    }
    float inv = 0.2f / L;
    const float* xb = x + (size_t)b * NCH * NPIX + n;
    float* ob = out + (size_t)b * NCH * NPIX + n;
    #pragma unroll
    for (int c = 0; c < NCH; ++c)
        ob[(size_t)c * NPIX] = fmaf(inv, o[c], xb[(size_t)c * NPIX]);
}

// ---------------------------------------------------------------------------
extern "C" void kernel_launch(void* const* d_in, const int* in_sizes, int n_in,
                              void* d_out, int out_size, void* d_ws, size_t ws_size,
                              hipStream_t stream) {
    const float* x      = (const float*)d_in[0];
    const float* w_red  = (const float*)d_in[1];
    const float* b_red  = (const float*)d_in[2];
    const float* w_dil  = (const float*)d_in[3];
    const float* b_dil  = (const float*)d_in[4];
    const float* w_fuse = (const float*)d_in[5];
    const float* b_fuse = (const float*)d_in[6];
    float* out = (float*)d_out;
    float* ws  = (float*)d_ws;

    const size_t XRED_N = (size_t)BB * INNER * NPIX;
    const size_t TOK_N  = (size_t)BB * NPIX * NCH;
    int P = 0;
    const int cands[4] = {8, 4, 2, 1};
    for (int ci = 0; ci < 4; ++ci) {
        int cp = cands[ci];
        size_t need = (XRED_N + TOK_N + (size_t)BB * cp * NPIX * (2 + NCH)) * sizeof(float);
        if (ws_size >= need) { P = cp; break; }
    }
    if (P == 0) return;

    float* xred   = ws;
    float* tokens = xred + XRED_N;
    float* pm     = tokens + TOK_N;
    float* pl     = pm + (size_t)BB * P * NPIX;
    float* pacc   = pl + (size_t)BB * P * NPIX;

    k_reduce <<<(BB * NPIX + 255) / 256, 256, 0, stream>>>(x, w_red, b_red, xred);
    k_tokens <<<(BB * NPIX + 255) / 256, 256, 0, stream>>>(xred, w_dil, b_dil,
                                                           w_fuse, b_fuse, tokens);
    k_attn   <<<BB * P * (NPIX / 256), 256, 0, stream>>>(tokens, pm, pl, pacc, P, NPIX / P);
    k_combine<<<(BB * NPIX + 255) / 256, 256, 0, stream>>>(x, pm, pl, pacc, out, P);
}

// Round 3
// 236.412 us; speedup vs baseline: 6.0283x; 1.3329x over previous
//
#include <hip/hip_runtime.h>

#define HW    96
#define NPIX  9216        // 96*96
#define NCH   64          // C
#define INNER 3
#define NDIL  3
#define BB    2           // batch

typedef __attribute__((ext_vector_type(8))) short short8;            // 8 bf16
typedef __attribute__((ext_vector_type(8))) unsigned short ushort8;  // 8 bf16 raw
typedef __attribute__((ext_vector_type(4))) float f32x4;

__device__ __forceinline__ ushort f2bf_rne(float f) {
    unsigned u = __float_as_uint(f);
    u += 0x7fffu + ((u >> 16) & 1u);
    return (ushort)(u >> 16);
}
__device__ __forceinline__ ushort f2bf_trunc(float f) {   // P in [0,1]; bias cancels in ratio
    return (ushort)(__float_as_uint(f) >> 16);
}
__device__ __forceinline__ float bf2f(ushort u) {
    return __uint_as_float((unsigned)u << 16);
}

// ---------------------------------------------------------------------------
// Kernel 1: x_red = 1x1 conv (64 -> 3 channels)
// ---------------------------------------------------------------------------
__global__ void k_reduce(const float* __restrict__ x, const float* __restrict__ w_red,
                         const float* __restrict__ b_red, float* __restrict__ xred) {
    int pix = blockIdx.x * blockDim.x + threadIdx.x;
    if (pix >= BB * NPIX) return;
    int b = pix / NPIX, n = pix % NPIX;
    float a0 = b_red[0], a1 = b_red[1], a2 = b_red[2];
    const float* xb = x + (size_t)b * NCH * NPIX + n;
    #pragma unroll
    for (int c = 0; c < NCH; ++c) {
        float xv = xb[(size_t)c * NPIX];
        a0 = fmaf(w_red[0 * NCH + c], xv, a0);
        a1 = fmaf(w_red[1 * NCH + c], xv, a1);
        a2 = fmaf(w_red[2 * NCH + c], xv, a2);
    }
    float* xr = xred + (size_t)b * INNER * NPIX + n;
    xr[0 * NPIX] = a0; xr[1 * NPIX] = a1; xr[2 * NPIX] = a2;
}

// ---------------------------------------------------------------------------
// Kernel 2 (lane=channel): wave = 1 pixel, lane = output channel.
// Conv + transforms computed redundantly per lane (cheap VALU); fuse conv is
// 54 FMA with conflict-free vector LDS reads of transposed weights wfT[j][c].
// Emits tokens ONLY as bf16, in both layouts: tok[b][n][c], tokT[b][c][n].
// ---------------------------------------------------------------------------
__global__ __launch_bounds__(256, 2) void
k_tokens(const float* __restrict__ xred,
         const float* __restrict__ w_dil, const float* __restrict__ b_dil,
         const float* __restrict__ w_fuse, const float* __restrict__ b_fuse,
         ushort* __restrict__ tok, ushort* __restrict__ tokT) {
    __shared__ float wfT[54 * NCH];        // [j][c], 13.8 KB
    __shared__ ushort tt[NCH * 4];         // transpose buffer: [c][local_pix]
    for (int i = threadIdx.x; i < 54 * NCH; i += 256) {
        int c = i / 54, j = i % 54;        // w_fuse is [C][54]
        wfT[j * NCH + c] = w_fuse[i];
    }
    __syncthreads();

    int wv = threadIdx.x >> 6, lane = threadIdx.x & 63;
    int pix = blockIdx.x * 4 + wv;         // 4 pixels per block, never straddles batch
    int b = pix / NPIX, n = pix % NPIX;
    int h = n / HW, w = n % HW;
    const float* xr = xred + (size_t)b * INNER * NPIX;

    float tf[6][INNER];
    #pragma unroll
    for (int o = 0; o < INNER; ++o) {
        const float* xo = xr + o * NPIX;
        tf[0][o] = xo[h * HW + w];
        tf[1][o] = xo[h * HW + (HW - 1 - w)];
        tf[2][o] = xo[(HW - 1 - h) * HW + w];
        tf[3][o] = xo[w * HW + (HW - 1 - h)];
        tf[4][o] = xo[(HW - 1 - h) * HW + (HW - 1 - w)];
        tf[5][o] = xo[(HW - 1 - w) * HW + h];
    }

    float co[NDIL][INNER];
    #pragma unroll
    for (int i = 0; i < NDIL; ++i) {
        int d = i + 1;
        #pragma unroll
        for (int o = 0; o < INNER; ++o) co[i][o] = b_dil[i * INNER + o];
        #pragma unroll
        for (int ci = 0; ci < INNER; ++ci) {
            const float* xo = xr + ci * NPIX;
            #pragma unroll
            for (int kh = 0; kh < 3; ++kh) {
                int hh = h + (kh - 1) * d;
                #pragma unroll
                for (int kw = 0; kw < 3; ++kw) {
                    int ww = w + (kw - 1) * d;
                    float v = ((unsigned)hh < HW && (unsigned)ww < HW) ? xo[hh * HW + ww] : 0.f;
                    #pragma unroll
                    for (int o = 0; o < INNER; ++o)
                        co[i][o] = fmaf(w_dil[((i * INNER + o) * INNER + ci) * 9 + kh * 3 + kw],
                                        v, co[i][o]);
                }
            }
        }
    }

    float f[54];
    #pragma unroll
    for (int i = 0; i < NDIL; ++i)
        #pragma unroll
        for (int t = 0; t < 6; ++t)
            #pragma unroll
            for (int o = 0; o < INNER; ++o)
                f[(i * 6 + t) * INNER + o] = co[i][o] * tf[t][o];

    // fuse conv: lane = channel. wfT read is a conflict-free stride-1 vector read.
    float acc = b_fuse[lane];
    #pragma unroll
    for (int j = 0; j < 54; ++j) acc = fmaf(wfT[j * NCH + lane], f[j], acc);

    ushort bfv = f2bf_rne(acc);
    tok[((size_t)b * NPIX + n) * NCH + lane] = bfv;   // coalesced 128 B per wave
    tt[lane * 4 + wv] = bfv;
    __syncthreads();
    if (threadIdx.x < NCH) {                          // wave 0 writes tokT in 8 B chunks
        int c = threadIdx.x;
        int n0 = (blockIdx.x * 4) % NPIX;
        int b0 = (blockIdx.x * 4) / NPIX;
        *(ushort4*)&tokT[((size_t)b0 * NCH + c) * NPIX + n0] = *(const ushort4*)&tt[c * 4];
    }
}

// ---------------------------------------------------------------------------
// Kernel 3: MFMA flash attention partials (bf16 16x16x32), transposed form:
// S^T = K·Q^T (softmax per col q = lane&15, per-lane scalar), O^T = V^T·P^T.
// 4 waves/wg x 64 q/wave; 64-key tiles; key range split P ways.
// Staging is a pure bf16 copy from precomputed tok/tokT (XOR-swizzled chunks).
// exp2 domain: 0.125*log2(e) folded into Q.
// ---------------------------------------------------------------------------
__global__ __launch_bounds__(256, 2) void
k_attn(const ushort* __restrict__ tok, const ushort* __restrict__ tokT,
       float* __restrict__ pm, float* __restrict__ pl, float* __restrict__ pacc,
       int P, int KP) {
    __shared__ ushort kt[64 * 64];      // [key][ch]  8 KB
    __shared__ ushort vt[64 * 64];      // [ch][key]  8 KB
    __shared__ ushort pt[4][64 * 64];   // per-wave P [q][key], 32 KB

    const int QW = NPIX / 256;          // 36 query chunks per batch
    int bid = blockIdx.x;
    int qc = bid % QW; int rest = bid / QW;
    int p = rest % P;  int b = rest / P;
    int tid = threadIdx.x;
    int wv = tid >> 6, lane = tid & 63;
    int quad = lane >> 4, l15 = lane & 15;

    const ushort* tb  = tok  + (size_t)b * NPIX * NCH;
    const ushort* tbT = tokT + (size_t)b * NCH * NPIX;
    int qwave = qc * 256 + wv * 64;

    // Q fragments: B operand of S^T (lane n=l15, k=quad*8+j+32kc); scale folded.
    short8 qf[4][2];
    const float scale = 0.125f * 1.44269504088896340736f;  // 1/sqrt(C) * log2(e)
    #pragma unroll
    for (int n = 0; n < 4; ++n) {
        const ushort* qr = tb + (size_t)(qwave + 16 * n + l15) * NCH + quad * 8;
        #pragma unroll
        for (int kc = 0; kc < 2; ++kc) {
            ushort8 raw = *(const ushort8*)(qr + 32 * kc);
            short8 f;
            #pragma unroll
            for (int e = 0; e < 8; ++e) f[e] = (short)f2bf_rne(bf2f(raw[e]) * scale);
            qf[n][kc] = f;
        }
    }

    f32x4 O[4][4];                      // O^T acc: D[c=16m+quad*4+reg][q=16n+l15]
    #pragma unroll
    for (int m = 0; m < 4; ++m)
        #pragma unroll
        for (int n = 0; n < 4; ++n) O[m][n] = (f32x4){0.f, 0.f, 0.f, 0.f};
    float mrun[4], lrun[4];
    #pragma unroll
    for (int n = 0; n < 4; ++n) { mrun[n] = -1e30f; lrun[n] = 0.f; }

    int k0 = p * KP;
    for (int kt0 = 0; kt0 < KP; kt0 += 64) {
        __syncthreads();                // all waves done with previous kt/vt
        // Stage: pure bf16 copies, 512 ushort8-chunks each, XOR-swizzled.
        #pragma unroll
        for (int ci = tid; ci < 512; ci += 256) {
            int row = ci >> 3, cc = ci & 7;
            ushort8 v = *(const ushort8*)(tb + (size_t)(k0 + kt0 + row) * NCH + cc * 8);
            *(ushort8*)&kt[row * 64 + ((cc ^ (row & 7)) * 8)] = v;
        }
        #pragma unroll
        for (int ci = tid; ci < 512; ci += 256) {
            int row = ci >> 3, cc = ci & 7;   // row = channel, cc = key-chunk
            ushort8 v = *(const ushort8*)(tbT + (size_t)row * NPIX + k0 + kt0 + cc * 8);
            *(ushort8*)&vt[row * 64 + ((cc ^ (row & 7)) * 8)] = v;
        }
        __syncthreads();

        // S^T = K·Q^T : D[key][q]; A from kt (lane m=key=16m+l15, k=ch)
        f32x4 S[4][4];
        #pragma unroll
        for (int m = 0; m < 4; ++m)
            #pragma unroll
            for (int n = 0; n < 4; ++n) S[m][n] = (f32x4){0.f, 0.f, 0.f, 0.f};
        #pragma unroll
        for (int kc = 0; kc < 2; ++kc) {
            short8 kf[4];
            #pragma unroll
            for (int m = 0; m < 4; ++m) {
                int row = 16 * m + l15;
                int cs = (quad + 4 * kc) ^ (row & 7);
                kf[m] = *(const short8*)&kt[row * 64 + cs * 8];
            }
            #pragma unroll
            for (int n = 0; n < 4; ++n)
                #pragma unroll
                for (int m = 0; m < 4; ++m)
                    S[m][n] = __builtin_amdgcn_mfma_f32_16x16x32_bf16(kf[m], qf[n][kc],
                                                                      S[m][n], 0, 0, 0);
        }

        // online softmax per query col (per-lane scalar)
        #pragma unroll
        for (int n = 0; n < 4; ++n) {
            float tmax = S[0][n][0];
            #pragma unroll
            for (int m = 0; m < 4; ++m)
                #pragma unroll
                for (int r = 0; r < 4; ++r) tmax = fmaxf(tmax, S[m][n][r]);
            tmax = fmaxf(tmax, __shfl_xor(tmax, 16, 64));
            tmax = fmaxf(tmax, __shfl_xor(tmax, 32, 64));
            float mn = fmaxf(mrun[n], tmax);
            float alpha = __builtin_amdgcn_exp2f(mrun[n] - mn);
            mrun[n] = mn;
            lrun[n] *= alpha;
            #pragma unroll
            for (int m = 0; m < 4; ++m) {
                O[m][n][0] *= alpha; O[m][n][1] *= alpha;
                O[m][n][2] *= alpha; O[m][n][3] *= alpha;
            }
            int q = 16 * n + l15;
            #pragma unroll
            for (int m = 0; m < 4; ++m) {
                float p0 = __builtin_amdgcn_exp2f(S[m][n][0] - mn);
                float p1 = __builtin_amdgcn_exp2f(S[m][n][1] - mn);
                float p2 = __builtin_amdgcn_exp2f(S[m][n][2] - mn);
                float p3 = __builtin_amdgcn_exp2f(S[m][n][3] - mn);
                lrun[n] += (p0 + p1) + (p2 + p3);
                ushort4 w;
                w.x = f2bf_trunc(p0); w.y = f2bf_trunc(p1);
                w.z = f2bf_trunc(p2); w.w = f2bf_trunc(p3);
                int chunk = 2 * m + (quad >> 1);         // keys 16m+quad*4..+3
                int cs = chunk ^ (q & 7);
                *(ushort4*)&pt[wv][q * 64 + cs * 8 + (quad & 1) * 4] = w;
            }
        }

        // O^T += V^T·P^T : A from vt (m=ch), B from pt (n=q, k=key)
        #pragma unroll
        for (int kc = 0; kc < 2; ++kc) {
            short8 af[4];
            #pragma unroll
            for (int m = 0; m < 4; ++m) {
                int ch = 16 * m + l15;
                int cs = (quad + 4 * kc) ^ (ch & 7);
                af[m] = *(const short8*)&vt[ch * 64 + cs * 8];
            }
            #pragma unroll
            for (int n = 0; n < 4; ++n) {
                int q = 16 * n + l15;
                int cs = (quad + 4 * kc) ^ (q & 7);
                short8 bfr = *(const short8*)&pt[wv][q * 64 + cs * 8];
                #pragma unroll
                for (int m = 0; m < 4; ++m)
                    O[m][n] = __builtin_amdgcn_mfma_f32_16x16x32_bf16(af[m], bfr,
                                                                      O[m][n], 0, 0, 0);
            }
        }
    }

    #pragma unroll
    for (int n = 0; n < 4; ++n) {       // disjoint key subsets per quad
        lrun[n] += __shfl_xor(lrun[n], 16, 64);
        lrun[n] += __shfl_xor(lrun[n], 32, 64);
    }
    size_t bpb = ((size_t)b * P + p) * NPIX;
    if (quad == 0) {
        #pragma unroll
        for (int n = 0; n < 4; ++n) {
            int qg = qwave + 16 * n + l15;
            pm[bpb + qg] = mrun[n];
            pl[bpb + qg] = lrun[n];
        }
    }
    #pragma unroll
    for (int n = 0; n < 4; ++n) {
        int qg = qwave + 16 * n + l15;
        float* dst = pacc + (bpb + qg) * NCH;
        #pragma unroll
        for (int m = 0; m < 4; ++m)
            *(float4*)(dst + 16 * m + quad * 4) =
                make_float4(O[m][n][0], O[m][n][1], O[m][n][2], O[m][n][3]);
    }
}

// ---------------------------------------------------------------------------
// Kernel 4: merge P partials (exp2 domain) + residual, 4-way channel split.
// thread -> (pixel, channel quarter). out = x + 0.2*attn (NCHW).
// ---------------------------------------------------------------------------
__global__ void k_combine(const float* __restrict__ x, const float* __restrict__ pm,
                          const float* __restrict__ pl, const float* __restrict__ pacc,
                          float* __restrict__ out, int P) {
    int gid = blockIdx.x * blockDim.x + threadIdx.x;
    if (gid >= BB * NPIX * 4) return;
    int pix = gid >> 2, cq = gid & 3;
    int b = pix / NPIX, n = pix % NPIX;
    int c0 = cq * 16;
    float M = -1e30f;
    for (int p = 0; p < P; ++p) M = fmaxf(M, pm[((size_t)b * P + p) * NPIX + n]);
    float L = 0.f;
    float o[16];
    #pragma unroll
    for (int i = 0; i < 16; ++i) o[i] = 0.f;
    for (int p = 0; p < P; ++p) {
        size_t base = ((size_t)b * P + p) * NPIX + n;
        float fct = __builtin_amdgcn_exp2f(pm[base] - M);
        L += pl[base] * fct;
        const float4* pa = (const float4*)(pacc + base * NCH + c0);
        #pragma unroll
        for (int v = 0; v < 4; ++v) {
            float4 t = pa[v];
            o[4*v+0] = fmaf(fct, t.x, o[4*v+0]);
            o[4*v+1] = fmaf(fct, t.y, o[4*v+1]);
            o[4*v+2] = fmaf(fct, t.z, o[4*v+2]);
            o[4*v+3] = fmaf(fct, t.w, o[4*v+3]);
        }
    }
    float inv = 0.2f / L;
    const float* xb = x + ((size_t)b * NCH + c0) * NPIX + n;
    float* ob = out + ((size_t)b * NCH + c0) * NPIX + n;
    #pragma unroll
    for (int i = 0; i < 16; ++i)
        ob[(size_t)i * NPIX] = fmaf(inv, o[i], xb[(size_t)i * NPIX]);
}

// ---------------------------------------------------------------------------
extern "C" void kernel_launch(void* const* d_in, const int* in_sizes, int n_in,
                              void* d_out, int out_size, void* d_ws, size_t ws_size,
                              hipStream_t stream) {
    const float* x      = (const float*)d_in[0];
    const float* w_red  = (const float*)d_in[1];
    const float* b_red  = (const float*)d_in[2];
    const float* w_dil  = (const float*)d_in[3];
    const float* b_dil  = (const float*)d_in[4];
    const float* w_fuse = (const float*)d_in[5];
    const float* b_fuse = (const float*)d_in[6];
    float* out = (float*)d_out;

    // ws layout: xred f32 | tok bf16 | tokT bf16 | pm | pl | pacc f32
    const size_t XRED_N = (size_t)BB * INNER * NPIX;       //    55,296 f32
    const size_t TOK_N  = (size_t)BB * NPIX * NCH;         // 1,179,648 bf16 (x2 layouts)
    const size_t HEAD_B = XRED_N * 4 + 2 * TOK_N * 2;      // bytes before partials
    int P = 0;
    const int cands[6] = {16, 12, 8, 4, 2, 1};
    for (int ci = 0; ci < 6; ++ci) {
        int cp = cands[ci];
        size_t need = HEAD_B + (size_t)BB * cp * NPIX * (2 + NCH) * 4;
        if (ws_size >= need) { P = cp; break; }
    }
    if (P == 0) return;

    float*  xred = (float*)d_ws;
    ushort* tok  = (ushort*)(xred + XRED_N);
    ushort* tokT = tok + TOK_N;
    float*  pm   = (float*)(tokT + TOK_N);
    float*  pl   = pm + (size_t)BB * P * NPIX;
    float*  pacc = pl + (size_t)BB * P * NPIX;

    k_reduce <<<(BB * NPIX + 255) / 256, 256, 0, stream>>>(x, w_red, b_red, xred);
    k_tokens <<<BB * NPIX / 4, 256, 0, stream>>>(xred, w_dil, b_dil, w_fuse, b_fuse,
                                                 tok, tokT);
    k_attn   <<<BB * P * (NPIX / 256), 256, 0, stream>>>(tok, tokT, pm, pl, pacc,
                                                         P, NPIX / P);
    k_combine<<<(BB * NPIX * 4 + 255) / 256, 256, 0, stream>>>(x, pm, pl, pacc, out, P);
}